// Round 21
// baseline (184.538 us; speedup 1.0000x reference)
//
#include <hip/hip_runtime.h>

// Problem constants (match reference)
#define K_     1056
#define N_     2112
#define M_     1056   // N - K
#define E_     6336   // M * 6
#define NIE_   5280   // M * 5 info-side edges (the only BP state)
#define CAP_   6336   // padded c2v extent upper bound (stride = d|1 adds <=1/VN)
#define ALL_   7392   // CAP_ + K_ : c2v + marg unified array
#define DV_    5
#define ROW_   6      // edge 6m+5 is the parity VN K+m
#define NSYM_  528
#define NITER_ 20
#define BATCH_ 1024
#define BS_    512    // 8 waves/block -> 4 blocks/CU fills all 32 wave slots

#define LOG2E_ 1.4426950408889634f
#define AVLO_  (1e-6f * LOG2E_)          // |v2c| floor, bits units
#define AVHI_  (20.0f * LOG2E_)          // |v2c| cap,  bits units
#define QC_    0.99999988f               // tanh-domain cap (unchanged)

// stride(d) = d | 1 : always ODD -> coprime with 32 banks -> Phase A's
// wave-uniform-stride segment reads are conflict-free.
__device__ __forceinline__ int seg_stride(int d) { return d | 1; }

// Bare-instruction transcendentals (R17 win). Inputs always normal-range.
__device__ __forceinline__ float fexp2(float x) { return __builtin_amdgcn_exp2f(x); }
__device__ __forceinline__ float flog2(float x) { return __builtin_amdgcn_logf(x); }
__device__ __forceinline__ float frcp(float x)  { return __builtin_amdgcn_rcpf(x); }

// -------------------------------------------------------------------------
// Single kernel, one block per codeword, 512 threads / 8 waves.
// == R17/R19 structure + R20: 3-transcendental CN update ==
//
// R20: the ~2x gap between measured busy cycles (218K/SIMD) and the
// full-rate-VALU model points at the quarter-width trans pipe as the
// binding resource. The CN update is refactored to carry numerator and
// denominator of t = (1-e)/(1+e) SEPARATELY through the extrinsic
// product:  n = copysign(1-e, v2c), d = 1+e  (no per-edge rcp);
// prefix/suffix products give N_j, D_j (seeded with parity n5,d5);
// clamp N_j to +-QC*D_j (same semantics as clamping q to +-QC);
// r = log2(D_j+N_j) - log2(D_j-N_j)   (the final rcp vanishes too).
// Per edge: 1 exp2 + 2 log2 (was exp2 + log2 + 2 rcp). ULP-class
// rounding change — same envelope validated absmax-0 since R1.
//
// LDS ~30 KB: s_all[7392]: build: [0..N) staging, [N..N+4K) int scratch;
//   BP: [0..CAP) c2v odd-stride VN-major segments, [CAP..) marginals.
//
// Structure: H = [A | I]; parity VN deg-1 -> per-check constants n5,d5;
// degree-sorted slots (wave-uniform Phase A); scan-free bases from 32-bin
// histogram; atomic build order only permutes accumulation order
// (validated order-independent R4-R19, absmax 0). R18 lesson: sequential
// float segments beat index-CSR gather in Phase A.
// -------------------------------------------------------------------------
__global__ __launch_bounds__(BS_, 8) void link_kernel(
    const int*   __restrict__ bits,      // [B,K]
    const int*   __restrict__ a_idx,     // [M,DV]
    const float* __restrict__ points_re, // [16]
    const float* __restrict__ points_im, // [16]
    const float* __restrict__ noise_re,  // [B,NSYM]
    const float* __restrict__ noise_im,  // [B,NSYM]
    const float* __restrict__ ebno_db,   // [1]
    const int*   __restrict__ edge_vn,   // [E]
    float*       __restrict__ out)       // [2,B,K]
{
#pragma clang fp contract(off)
    const int b   = blockIdx.x;
    const int tid = threadIdx.x;

    __shared__ float s_all[ALL_];
    __shared__ float s_pre[16];
    __shared__ float s_pim[16];
    __shared__ int   s_hist[32];
    __shared__ int   s_binStart[32];
    __shared__ int   s_binBase[32];

    float* s_mem  = s_all;               // staging, later c2v [0..CAP)
    float* s_marg = s_all + CAP_;        // BP marginals [CAP..ALL)

    // build scratch aliases [N..N+4K) (inside s_all; demap uses [0..N))
    int* sc        = (int*)(s_all + N_);
    int* s_deg     = sc;                 // [K] degree
    int* s_perm    = sc + K_;            // [K] slot -> v | deg<<16
    int* s_offslot = sc + 2 * K_;        // [K] v -> base | slot<<16
    int* s_cnt     = sc + 3 * K_;        // [K] edge-fill cursors

    if (tid < 16) {
        s_pre[tid] = points_re[tid];
        s_pim[tid] = points_im[tid];
    }
    if (tid < 32) s_hist[tid] = 0;

    const float eb    = ebno_db[0];
    const float no    = 1.0f / ((powf(10.0f, eb / 10.0f) * 0.5f) * 4.0f);
    const float sigma = sqrtf(no / 2.0f);

    // ---- stage info bits (0/1 floats); output0 = bits.astype(f32) ----
    for (int i = tid; i < K_; i += BS_) {
        int v = bits[b * K_ + i];
        s_mem[i] = (float)v;
        out[b * K_ + i] = (float)v;
    }
    __syncthreads();

    // ---- parity: XOR of DV gathered info bits; zero build counters ----
    for (int m = tid; m < M_; m += BS_) {
        float acc = 0.0f;
        #pragma unroll
        for (int d = 0; d < DV_; ++d) acc += s_mem[a_idx[m * DV_ + d]];
        s_mem[K_ + m] = (float)(((int)acc) & 1);
    }
    for (int v = tid; v < K_; v += BS_) { s_deg[v] = 0; s_cnt[v] = 0; }
    __syncthreads();

    // ---- QAM + AWGN + exact APP demap, per-bit streaming (R19) ----
    // ---- overlapped: VN degree count (disjoint LDS region)       ----
    for (int s = tid; s < NSYM_; s += BS_) {
        int c0 = (int)s_mem[4 * s + 0];
        int c1 = (int)s_mem[4 * s + 1];
        int c2 = (int)s_mem[4 * s + 2];
        int c3 = (int)s_mem[4 * s + 3];
        int sym = c0 * 8 + c1 * 4 + c2 * 2 + c3;
        float yre = s_pre[sym] + sigma * noise_re[b * NSYM_ + s];
        float yim = s_pim[sym] + sigma * noise_im[b * NSYM_ + s];
        #pragma unroll
        for (int j = 0; j < 4; ++j) {
            float m0 = -1e30f, m1 = -1e30f;
            #pragma unroll
            for (int p = 0; p < 16; ++p) {
                float dre  = yre - s_pre[p];
                float dim_ = yim - s_pim[p];
                float lg   = -(dre * dre + dim_ * dim_) / no;
                if (((p >> (3 - j)) & 1) == 0) m0 = fmaxf(m0, lg);
                else                           m1 = fmaxf(m1, lg);
            }
            float sum0 = 0.0f, sum1 = 0.0f;
            #pragma unroll
            for (int p = 0; p < 16; ++p) {
                float dre  = yre - s_pre[p];
                float dim_ = yim - s_pim[p];
                float lg   = -(dre * dre + dim_ * dim_) / no;
                if (((p >> (3 - j)) & 1) == 0) sum0 += __expf(lg - m0);
                else                           sum1 += __expf(lg - m1);
            }
            float llr = (m0 + __logf(sum0)) - (m1 + __logf(sum1));
            s_mem[4 * s + j] = llr * LOG2E_;
        }
    }
    for (int idx = tid; idx < NIE_; idx += BS_) {
        int m = idx / 5, j = idx - m * 5;
        atomicAdd(&s_deg[edge_vn[m * ROW_ + j]], 1);
    }
    __syncthreads();

    // ---- degree histogram -> arithmetic segment bases (scan-free) ----
    for (int v = tid; v < K_; v += BS_) atomicAdd(&s_hist[s_deg[v] & 31], 1);
    __syncthreads();
    if (tid == 0) {
        int accS = 0, accB = 0;
        for (int d = 0; d < 32; ++d) {
            int c = s_hist[d];
            s_binStart[d] = accS;
            s_binBase[d]  = accB;
            s_hist[d]     = accS;        // reuse as sort cursor
            accS += c;
            accB += c * seg_stride(d);   // odd stride -> conflict-free
        }
    }
    __syncthreads();
    for (int v = tid; v < K_; v += BS_) {   // counting sort by degree
        int d    = s_deg[v];
        int slot = atomicAdd(&s_hist[d & 31], 1);
        int base = s_binBase[d] + (slot - s_binStart[d]) * seg_stride(d);
        s_perm[slot]  = v | (d << 16);
        s_offslot[v]  = base | (slot << 16);
    }
    __syncthreads();

    // ---- capture iteration-invariant state in registers ----
    int      pv[3];                      // slot -> VN id
    unsigned od[3];                      // base | deg<<16
    float    lr[3];                      // channel LLR_hat of owned VN
    #pragma unroll
    for (int k = 0; k < 3; ++k) {
        int s = tid + BS_ * k;
        if (s < K_) {
            int w = s_perm[s];
            int v = w & 0xFFFF;
            int d = w >> 16;
            int base = s_binBase[d] + (s - s_binStart[d]) * seg_stride(d);
            pv[k] = v;
            od[k] = (unsigned)base | ((unsigned)d << 16);
            lr[k] = s_mem[v];
        } else { pv[k] = 0; od[k] = 0; lr[k] = 0.0f; }
    }
    float    n5[3], d5[3];               // parity num/den constants
    unsigned vnp[3][5];                  // slot | pos<<16
    #pragma unroll
    for (int kk = 0; kk < 3; ++kk) {
        int m = tid + BS_ * kk;
        if (m < M_) {
            #pragma unroll
            for (int j = 0; j < 5; ++j) {
                int v = edge_vn[m * ROW_ + j];
                int r = atomicAdd(&s_cnt[v], 1);
                int w = s_offslot[v];
                vnp[kk][j]  = (unsigned)(w >> 16) | ((unsigned)((w & 0xFFFF) + r) << 16);
            }
            float lrP = s_mem[K_ + m];
            float av  = __builtin_amdgcn_fmed3f(fabsf(lrP), AVLO_, AVHI_);
            float e   = fexp2(-av);
            n5[kk] = copysignf(1.0f - e, lrP);
            d5[kk] = 1.0f + e;
        } else { n5[kk] = 1.0f; d5[kk] = 1.0f; }
    }
    __syncthreads();
    // scratch fully consumed -> become the message array
    for (int i = tid; i < CAP_; i += BS_) s_mem[i] = 0.0f;
    __syncthreads();

    // ---- sum-product BP, flooding (bits domain) ----
    for (int it = 0; it < NITER_; ++it) {
        // Phase A: slot-indexed marginals; odd-stride sequential segments
        #pragma unroll
        for (int k = 0; k < 3; ++k) {
            int s = tid + BS_ * k;
            if (s < K_) {
                int base = (int)(od[k] & 0xFFFFu);
                int dg   = (int)(od[k] >> 16);
                float mg = lr[k];
                int d = 0;
                for (; d + 1 < dg; d += 2) {
                    mg += s_mem[base + d];
                    mg += s_mem[base + d + 1];
                }
                if (d < dg) mg += s_mem[base + d];
                s_marg[s] = mg;
            }
        }
        __syncthreads();
        // Phase B: CN update, num/den split — 1 exp2 + 2 log2 per edge,
        // zero rcp. Old c2v re-read from LDS (single writer per position).
        #pragma unroll
        for (int kk = 0; kk < 3; ++kk) {
            int m = tid + BS_ * kk;
            if (m < M_) {
                float nj[5], dj[5];
                #pragma unroll
                for (int j = 0; j < 5; ++j) {
                    unsigned w = vnp[kk][j];
                    float v2c = s_marg[w & 0xFFFFu] - s_mem[w >> 16];
                    float av  = __builtin_amdgcn_fmed3f(fabsf(v2c), AVLO_, AVHI_);
                    float e   = fexp2(-av);
                    nj[j] = copysignf(1.0f - e, v2c);
                    dj[j] = 1.0f + e;
                }
                float qn[5], qd[5];
                float pn = n5[kk], pd = d5[kk];
                #pragma unroll
                for (int j = 0; j < 5; ++j) {
                    qn[j] = pn; pn *= nj[j];
                    qd[j] = pd; pd *= dj[j];
                }
                float sn = 1.0f, sd = 1.0f;
                #pragma unroll
                for (int j = 4; j >= 0; --j) {
                    qn[j] *= sn; sn *= nj[j];
                    qd[j] *= sd; sd *= dj[j];
                }
                #pragma unroll
                for (int j = 0; j < 5; ++j) {
                    float D   = qd[j];
                    float lim = QC_ * D;
                    float Nc  = __builtin_amdgcn_fmed3f(qn[j], -lim, lim);
                    float r   = flog2(D + Nc) - flog2(D - Nc);
                    s_mem[vnp[kk][j] >> 16] = r;
                }
            }
        }
        __syncthreads();
    }

    // ---- final marginal + hard decision on info VNs ----
    #pragma unroll
    for (int k = 0; k < 3; ++k) {
        int s = tid + BS_ * k;
        if (s < K_) {
            int base = (int)(od[k] & 0xFFFFu);
            int dg   = (int)(od[k] >> 16);
            float mg = lr[k];
            int d = 0;
            for (; d + 1 < dg; d += 2) {
                mg += s_mem[base + d];
                mg += s_mem[base + d + 1];
            }
            if (d < dg) mg += s_mem[base + d];
            out[(size_t)BATCH_ * K_ + b * K_ + pv[k]] = (mg < 0.0f) ? 1.0f : 0.0f;
        }
    }
}

extern "C" void kernel_launch(void* const* d_in, const int* in_sizes, int n_in,
                              void* d_out, int out_size, void* d_ws, size_t ws_size,
                              hipStream_t stream) {
    const int*   bits    = (const int*)  d_in[0];
    const int*   a_idx   = (const int*)  d_in[1];
    // d_in[2] = edge_cn (implicit: contiguous groups of 6) — unused
    const int*   edge_vn = (const int*)  d_in[3];
    const float* pre     = (const float*)d_in[4];
    const float* pim     = (const float*)d_in[5];
    const float* nre     = (const float*)d_in[6];
    const float* nim     = (const float*)d_in[7];
    const float* ebno    = (const float*)d_in[8];

    link_kernel<<<BATCH_, BS_, 0, stream>>>(bits, a_idx, pre, pim, nre, nim,
                                            ebno, edge_vn, (float*)d_out);
}